// Round 7
// baseline (335.344 us; speedup 1.0000x reference)
//
#include <hip/hip_runtime.h>
#include <hip/hip_bf16.h>

#define NN 512
#define NFG 128
#define NFR 64
#define BT 256

typedef __attribute__((ext_vector_type(8))) short bfrag;   // 8 bf16
typedef __attribute__((ext_vector_type(4))) float f32x4;

__device__ __forceinline__ short f2bf(float f) {
    unsigned u = __float_as_uint(f);
    return (short)((u + 0x7fffu + ((u >> 16) & 1u)) >> 16);
}

// ---------------------------------------------------------------------------
// k_prep: WtB[g][f] = bf16(W[f][g])
__global__ __launch_bounds__(256) void k_prep(const float* __restrict__ W,
                                              short* __restrict__ WtB) {
    int i = blockIdx.x * 256 + threadIdx.x;
    if (i < NFG * NFG) { int f = i >> 7, g = i & 127; WtB[g * NFG + f] = f2bf(W[i]); }
}

// ---------------------------------------------------------------------------
// k_projF: theta = X@thw^T + thb ; phi = X@phw^T + phb ; Yt = (X@W)^T
__global__ __launch_bounds__(256) void k_projF(const float* __restrict__ X,
                                               const float* __restrict__ thw,
                                               const float* __restrict__ thb,
                                               const float* __restrict__ phw,
                                               const float* __restrict__ phb,
                                               const short* __restrict__ WtB,
                                               short* __restrict__ thetaS,
                                               short* __restrict__ phiS,
                                               short* __restrict__ YtG) {
    __shared__ short Xs[64][136];
    __shared__ short wS[2][64][136];
    __shared__ float bS[2][64];
    const int bt = blockIdx.y, n0 = blockIdx.x * 64, tid = threadIdx.x;

    {   // stage X tile (f32 -> bf16)
        int row = tid >> 2, seg = tid & 3;
        const float* src = X + ((size_t)(bt * NN + n0 + row)) * NFG + seg * 32;
        short tmp[32];
        #pragma unroll
        for (int k = 0; k < 8; ++k) {
            float4 v = reinterpret_cast<const float4*>(src)[k];
            tmp[k*4+0] = f2bf(v.x); tmp[k*4+1] = f2bf(v.y);
            tmp[k*4+2] = f2bf(v.z); tmp[k*4+3] = f2bf(v.w);
        }
        #pragma unroll
        for (int k = 0; k < 4; ++k)
            reinterpret_cast<uint4*>(&Xs[row][seg * 32])[k] =
                reinterpret_cast<uint4*>(tmp)[k];
    }
    #pragma unroll
    for (int k = 0; k < 32; ++k) {
        int idx = k * 256 + tid;
        int r = idx >> 7, f = idx & 127;
        wS[0][r][f] = f2bf(thw[idx]);
        wS[1][r][f] = f2bf(phw[idx]);
    }
    if (tid < 64) { bS[0][tid] = thb[tid]; bS[1][tid] = phb[tid]; }
    __syncthreads();

    const int wid = tid >> 6, lane = tid & 63;
    const int l16 = lane & 15, lg = lane >> 4;

    bfrag xa[4];
    #pragma unroll
    for (int kk = 0; kk < 4; ++kk)
        xa[kk] = *reinterpret_cast<const bfrag*>(&Xs[wid * 16 + l16][kk * 32 + lg * 8]);

    for (int pass = 0; pass < 2; ++pass) {
        short* dst = pass ? phiS : thetaS;
        #pragma unroll
        for (int c = 0; c < 4; ++c) {
            f32x4 acc = {0.f, 0.f, 0.f, 0.f};
            #pragma unroll
            for (int kk = 0; kk < 4; ++kk) {
                bfrag b = *reinterpret_cast<const bfrag*>(
                    &wS[pass][c * 16 + l16][kk * 32 + lg * 8]);
                acc = __builtin_amdgcn_mfma_f32_16x16x32_bf16(xa[kk], b, acc, 0, 0, 0);
            }
            float bv = bS[pass][c * 16 + l16];
            #pragma unroll
            for (int r = 0; r < 4; ++r) {
                int n = n0 + wid * 16 + lg * 4 + r;
                dst[((size_t)(bt * NN + n)) * NFR + c * 16 + l16] = f2bf(acc[r] + bv);
            }
        }
    }

    // Yt[g][m] = sum_f Wt[g][f] * X[m][f]
    #pragma unroll
    for (int gi = 0; gi < 2; ++gi) {
        int gs = wid * 2 + gi;
        bfrag wa[4];
        #pragma unroll
        for (int kk = 0; kk < 4; ++kk)
            wa[kk] = *reinterpret_cast<const bfrag*>(
                &WtB[(gs * 16 + l16) * NFG + kk * 32 + lg * 8]);
        #pragma unroll
        for (int ms = 0; ms < 4; ++ms) {
            f32x4 acc = {0.f, 0.f, 0.f, 0.f};
            #pragma unroll
            for (int kk = 0; kk < 4; ++kk) {
                bfrag xb = *reinterpret_cast<const bfrag*>(
                    &Xs[ms * 16 + l16][kk * 32 + lg * 8]);
                acc = __builtin_amdgcn_mfma_f32_16x16x32_bf16(wa[kk], xb, acc, 0, 0, 0);
            }
            #pragma unroll
            for (int r = 0; r < 4; ++r) {
                int g = gs * 16 + lg * 4 + r;
                int m = n0 + ms * 16 + l16;
                YtG[((size_t)(bt * NFG + g)) * NN + m] = f2bf(acc[r]);
            }
        }
    }
}

// ---------------------------------------------------------------------------
// k_fused (streaming, two-pass, no-max-sub softmax):
//   each wave owns 16 n-rows; pass1: QK + mask -> bitmask + exp-sum;
//   pass2: recompute QK -> p = exp*inv -> rg write (f32, coalesced) ->
//          per-wave LDS chunk staging -> PV (out = P @ Yt from global).
//   LDS 9.2 KB, 1 barrier, 8 blocks/CU target.
__global__ __launch_bounds__(256, 8) void k_fused(const short* __restrict__ thetaS,
                                                  const short* __restrict__ phiS,
                                                  const short* __restrict__ YtG,
                                                  const float* __restrict__ boxes,
                                                  float* __restrict__ outG,
                                                  float* __restrict__ rgG) {
    __shared__ float2 c2[NN];              // 4 KB centers (cx,cy interleaved)
    __shared__ short stageAll[4][16 * 40]; // 5 KB: per-wave [16 n][40] bf16 tile

    // XCD swizzle: the 8 n-blocks of a frame land on one XCD
    const int bid = blockIdx.x;            // 0..2047
    const int jj = bid >> 3;
    const int bt = (bid & 7) * 32 + (jj >> 3);
    const int n0 = (jj & 7) * 64;
    const int tid = threadIdx.x;
    const int wid = tid >> 6, lane = tid & 63;
    const int l16 = lane & 15, lg = lane >> 4;

    {   // centers, bit-exact vs numpy f32 RNE
        float4 b0 = reinterpret_cast<const float4*>(boxes)[bt * NN + tid];
        float4 b1 = reinterpret_cast<const float4*>(boxes)[bt * NN + 256 + tid];
        c2[tid]       = make_float2(__fmul_rn(__fadd_rn(b0.x, b0.z), 0.5f),
                                    __fmul_rn(__fadd_rn(b0.y, b0.w), 0.5f));
        c2[tid + 256] = make_float2(__fmul_rn(__fadd_rn(b1.x, b1.z), 0.5f),
                                    __fmul_rn(__fadd_rn(b1.y, b1.w), 0.5f));
    }
    const int nw = n0 + wid * 16;          // wave's first n row
    const size_t fr = (size_t)bt * NN;

    // theta B-frags for this wave's 16 n (col = l16)
    bfrag thB0 = *reinterpret_cast<const bfrag*>(&thetaS[(fr + nw + l16) * NFR + lg * 8]);
    bfrag thB1 = *reinterpret_cast<const bfrag*>(&thetaS[(fr + nw + l16) * NFR + 32 + lg * 8]);
    __syncthreads();                       // the ONLY barrier

    const float2 cn = c2[nw + l16];        // this lane's n-center
    const float THRv = __uint_as_float(0x43800001u);  // 256 + 2^-15

    // -------- pass 1: exp-sum + mask bits (no S materialization) ----------
    unsigned mw[4] = {0u, 0u, 0u, 0u};
    float sm = 0.f;
    #pragma unroll 2
    for (int t = 0; t < 32; ++t) {
        const short* prow = &phiS[(fr + t * 16 + l16) * NFR + lg * 8];
        bfrag pa0 = *reinterpret_cast<const bfrag*>(prow);
        bfrag pa1 = *reinterpret_cast<const bfrag*>(prow + 32);
        f32x4 acc = {0.f, 0.f, 0.f, 0.f};
        acc = __builtin_amdgcn_mfma_f32_16x16x32_bf16(pa0, thB0, acc, 0, 0, 0);
        acc = __builtin_amdgcn_mfma_f32_16x16x32_bf16(pa1, thB1, acc, 0, 0, 0);
        float4 cA = *reinterpret_cast<const float4*>(&c2[t * 16 + lg * 4]);
        float4 cB = *reinterpret_cast<const float4*>(&c2[t * 16 + lg * 4 + 2]);
        #pragma unroll
        for (int r = 0; r < 4; ++r) {
            float cx = (r == 0) ? cA.x : (r == 1) ? cA.z : (r == 2) ? cB.x : cB.z;
            float cy = (r == 0) ? cA.y : (r == 1) ? cA.w : (r == 2) ? cB.y : cB.w;
            // masked <=> sqrt_RNE(d2) > 16.0f <=> d2 > 256+2^-15
            float dx = __fsub_rn(cn.x, cx), dy = __fsub_rn(cn.y, cy);
            float d2 = __fadd_rn(__fmul_rn(dx, dx), __fmul_rn(dy, dy));
            bool msk = d2 > THRv;
            float e = msk ? 0.f : __expf(acc[r] * 0.125f);   // |sim|<~3: no max-sub
            sm += e;
            mw[t >> 3] |= (msk ? 1u : 0u) << (((t & 7) << 2) | r);
        }
    }
    sm += __shfl_xor(sm, 16);
    sm += __shfl_xor(sm, 32);
    const float inv = 1.0f / sm;

    // -------- pass 2: recompute -> rg + staged PV --------------------------
    f32x4 pool[8];
    #pragma unroll
    for (int gt = 0; gt < 8; ++gt) pool[gt] = f32x4{0.f, 0.f, 0.f, 0.f};
    short* st = stageAll[wid];
    const short* ytb = &YtG[(size_t)bt * NFG * NN];

    #pragma unroll 1
    for (int c = 0; c < 16; ++c) {
        #pragma unroll
        for (int h = 0; h < 2; ++h) {
            const int t = c * 2 + h;
            const short* prow = &phiS[(fr + t * 16 + l16) * NFR + lg * 8];
            bfrag pa0 = *reinterpret_cast<const bfrag*>(prow);
            bfrag pa1 = *reinterpret_cast<const bfrag*>(prow + 32);
            f32x4 acc = {0.f, 0.f, 0.f, 0.f};
            acc = __builtin_amdgcn_mfma_f32_16x16x32_bf16(pa0, thB0, acc, 0, 0, 0);
            acc = __builtin_amdgcn_mfma_f32_16x16x32_bf16(pa1, thB1, acc, 0, 0, 0);
            const unsigned bits = mw[t >> 3] >> ((t & 7) << 2);
            float p0 = (bits & 1u) ? 0.f : __expf(acc[0] * 0.125f) * inv;
            float p1 = (bits & 2u) ? 0.f : __expf(acc[1] * 0.125f) * inv;
            float p2 = (bits & 4u) ? 0.f : __expf(acc[2] * 0.125f) * inv;
            float p3 = (bits & 8u) ? 0.f : __expf(acc[3] * 0.125f) * inv;
            float4 pv = {p0, p1, p2, p3};
            *reinterpret_cast<float4*>(&rgG[(fr + nw + l16) * NN + t * 16 + lg * 4]) = pv;
            unsigned q0, q1;   // T12: RNE pack f32 pair -> 2 bf16
            asm("v_cvt_pk_bf16_f32 %0, %1, %2" : "=v"(q0) : "v"(p0), "v"(p1));
            asm("v_cvt_pk_bf16_f32 %0, %1, %2" : "=v"(q1) : "v"(p2), "v"(p3));
            uint2 qq; qq.x = q0; qq.y = q1;
            *reinterpret_cast<uint2*>(&st[l16 * 40 + h * 16 + lg * 4]) = qq;
        }
        // PV over this 32-m chunk (per-wave tile: no barrier, lgkmcnt only)
        bfrag pa = *reinterpret_cast<const bfrag*>(&st[l16 * 40 + lg * 8]);
        #pragma unroll
        for (int gt = 0; gt < 8; ++gt) {
            bfrag yb = *reinterpret_cast<const bfrag*>(
                &ytb[(gt * 16 + l16) * NN + c * 32 + lg * 8]);
            pool[gt] = __builtin_amdgcn_mfma_f32_16x16x32_bf16(pa, yb, pool[gt], 0, 0, 0);
        }
    }

    #pragma unroll
    for (int gt = 0; gt < 8; ++gt) {
        #pragma unroll
        for (int r = 0; r < 4; ++r) {
            outG[(fr + nw + lg * 4 + r) * NFG + gt * 16 + l16] = pool[gt][r];
        }
    }
}

// ---------------------------------------------------------------------------
// Fallback path (proven round-4 kernels), used only if ws is too small.
__global__ __launch_bounds__(256) void k_proj(const float* __restrict__ X,
                                              const float* __restrict__ thw,
                                              const float* __restrict__ thb,
                                              const float* __restrict__ phw,
                                              const float* __restrict__ phb,
                                              short* __restrict__ thetaS,
                                              short* __restrict__ phiS) {
    __shared__ short Xs[64][136];
    __shared__ short wS[2][64][136];
    __shared__ float bS[2][64];
    const int bt = blockIdx.y, n0 = blockIdx.x * 64, tid = threadIdx.x;
    {
        int row = tid >> 2, seg = tid & 3;
        const float* src = X + ((size_t)(bt * NN + n0 + row)) * NFG + seg * 32;
        short tmp[32];
        #pragma unroll
        for (int k = 0; k < 8; ++k) {
            float4 v = reinterpret_cast<const float4*>(src)[k];
            tmp[k*4+0] = f2bf(v.x); tmp[k*4+1] = f2bf(v.y);
            tmp[k*4+2] = f2bf(v.z); tmp[k*4+3] = f2bf(v.w);
        }
        #pragma unroll
        for (int k = 0; k < 4; ++k)
            reinterpret_cast<uint4*>(&Xs[row][seg * 32])[k] =
                reinterpret_cast<uint4*>(tmp)[k];
    }
    #pragma unroll
    for (int k = 0; k < 32; ++k) {
        int idx = k * 256 + tid;
        int r = idx >> 7, f = idx & 127;
        wS[0][r][f] = f2bf(thw[idx]);
        wS[1][r][f] = f2bf(phw[idx]);
    }
    if (tid < 64) { bS[0][tid] = thb[tid]; bS[1][tid] = phb[tid]; }
    __syncthreads();
    const int wid = tid >> 6, lane = tid & 63;
    const int l16 = lane & 15, lg = lane >> 4;
    bfrag xa[4];
    #pragma unroll
    for (int kk = 0; kk < 4; ++kk)
        xa[kk] = *reinterpret_cast<const bfrag*>(&Xs[wid * 16 + l16][kk * 32 + lg * 8]);
    for (int pass = 0; pass < 2; ++pass) {
        short* dst = pass ? phiS : thetaS;
        #pragma unroll
        for (int c = 0; c < 4; ++c) {
            f32x4 acc = {0.f, 0.f, 0.f, 0.f};
            #pragma unroll
            for (int kk = 0; kk < 4; ++kk) {
                bfrag b = *reinterpret_cast<const bfrag*>(
                    &wS[pass][c * 16 + l16][kk * 32 + lg * 8]);
                acc = __builtin_amdgcn_mfma_f32_16x16x32_bf16(xa[kk], b, acc, 0, 0, 0);
            }
            float bv = bS[pass][c * 16 + l16];
            #pragma unroll
            for (int r = 0; r < 4; ++r) {
                int n = n0 + wid * 16 + lg * 4 + r;
                dst[((size_t)(bt * NN + n)) * NFR + c * 16 + l16] = f2bf(acc[r] + bv);
            }
        }
    }
}

__global__ __launch_bounds__(512) void k_sim(const short* __restrict__ thetaS,
                                             const short* __restrict__ phiS,
                                             const float* __restrict__ boxes,
                                             float* __restrict__ rgG) {
    __shared__ float S[64][516];
    __shared__ float cxs[NN], cys[NN];
    const int bt = blockIdx.y, n0 = blockIdx.x * 64, tid = threadIdx.x;
    const int wid = tid >> 6, lane = tid & 63;
    const int l16 = lane & 15, lg = lane >> 4;
    const int rsub = wid & 3, ch = wid >> 2;
    {
        float4 b = reinterpret_cast<const float4*>(boxes)[bt * NN + tid];
        cxs[tid] = __fmul_rn(__fadd_rn(b.x, b.z), 0.5f);
        cys[tid] = __fmul_rn(__fadd_rn(b.y, b.w), 0.5f);
    }
    bfrag thA[2];
    #pragma unroll
    for (int kk = 0; kk < 2; ++kk)
        thA[kk] = *reinterpret_cast<const bfrag*>(
            &thetaS[((size_t)(bt * NN + n0 + rsub * 16 + l16)) * NFR + kk * 32 + lg * 8]);
    __syncthreads();
    #pragma unroll 1
    for (int mt = 0; mt < 8; ++mt) {
        int m0 = mt * 64;
        #pragma unroll
        for (int ci = 0; ci < 2; ++ci) {
            int cs = ch * 2 + ci;
            int m = m0 + cs * 16 + l16;
            f32x4 acc = {0.f, 0.f, 0.f, 0.f};
            #pragma unroll
            for (int kk = 0; kk < 2; ++kk) {
                bfrag pb = *reinterpret_cast<const bfrag*>(
                    &phiS[((size_t)(bt * NN + m)) * NFR + kk * 32 + lg * 8]);
                acc = __builtin_amdgcn_mfma_f32_16x16x32_bf16(thA[kk], pb, acc, 0, 0, 0);
            }
            float cxm = cxs[m], cym = cys[m];
            #pragma unroll
            for (int r = 0; r < 4; ++r) {
                int nl = rsub * 16 + lg * 4 + r;
                float dx = __fsub_rn(cxs[n0 + nl], cxm);
                float dy = __fsub_rn(cys[n0 + nl], cym);
                float d2 = __fadd_rn(__fmul_rn(dx, dx), __fmul_rn(dy, dy));
                S[nl][m] = (d2 > __uint_as_float(0x43800001u))
                               ? -__builtin_inff() : acc[r] * 0.125f;
            }
        }
    }
    __syncthreads();
    {
        int row = tid >> 3, j = tid & 7;
        float* Sp = &S[row][j * 64];
        float mx = -__builtin_inff();
        #pragma unroll
        for (int k = 0; k < 16; ++k) {
            float4 v = *reinterpret_cast<float4*>(Sp + k * 4);
            mx = fmaxf(mx, fmaxf(fmaxf(v.x, v.y), fmaxf(v.z, v.w)));
        }
        mx = fmaxf(mx, __shfl_xor(mx, 1));
        mx = fmaxf(mx, __shfl_xor(mx, 2));
        mx = fmaxf(mx, __shfl_xor(mx, 4));
        float sm = 0.f;
        #pragma unroll
        for (int k = 0; k < 16; ++k) {
            float4 v = *reinterpret_cast<float4*>(Sp + k * 4);
            v.x = __expf(v.x - mx); v.y = __expf(v.y - mx);
            v.z = __expf(v.z - mx); v.w = __expf(v.w - mx);
            sm += (v.x + v.y) + (v.z + v.w);
            *reinterpret_cast<float4*>(Sp + k * 4) = v;
        }
        sm += __shfl_xor(sm, 1);
        sm += __shfl_xor(sm, 2);
        sm += __shfl_xor(sm, 4);
        float inv = 1.0f / sm;
        float* rp = rgG + ((size_t)(bt * NN) + n0 + row) * NN + j * 64;
        #pragma unroll
        for (int k = 0; k < 16; ++k) {
            float4 a = *reinterpret_cast<float4*>(Sp + k * 4);
            a.x *= inv; a.y *= inv; a.z *= inv; a.w *= inv;
            *reinterpret_cast<float4*>(rp + k * 4) = a;
        }
    }
}

__global__ __launch_bounds__(256) void k_pool(const float* __restrict__ rgG,
                                              const float* __restrict__ X,
                                              const float* __restrict__ W,
                                              float* __restrict__ outG) {
    __shared__ short Xt[128][72];
    __shared__ short poolS[64][136];
    __shared__ short WtS[128][136];
    const int bt = blockIdx.y, n0 = blockIdx.x * 64, tid = threadIdx.x;
    const int wid = tid >> 6, lane = tid & 63;
    const int l16 = lane & 15, lg = lane >> 4;
    #pragma unroll
    for (int k = 0; k < 64; ++k) {
        int idx = k * 256 + tid;
        int f = idx >> 7, g = idx & 127;
        WtS[g][f] = f2bf(W[idx]);
    }
    f32x4 acc[8];
    #pragma unroll
    for (int ft = 0; ft < 8; ++ft) acc[ft] = f32x4{0.f, 0.f, 0.f, 0.f};
    #pragma unroll 1
    for (int mt = 0; mt < 8; ++mt) {
        __syncthreads();
        {
            int m = tid >> 2, seg = tid & 3;
            const float* src = X + ((size_t)(bt * NN + mt * 64 + m)) * NFG + seg * 32;
            #pragma unroll
            for (int k = 0; k < 8; ++k) {
                float4 v = reinterpret_cast<const float4*>(src)[k];
                int f = seg * 32 + k * 4;
                Xt[f + 0][m] = f2bf(v.x); Xt[f + 1][m] = f2bf(v.y);
                Xt[f + 2][m] = f2bf(v.z); Xt[f + 3][m] = f2bf(v.w);
            }
        }
        bfrag pa[2];
        const float* prow = rgG + ((size_t)(bt * NN + n0 + wid * 16 + l16)) * NN + mt * 64;
        #pragma unroll
        for (int kk = 0; kk < 2; ++kk) {
            float4 a = *reinterpret_cast<const float4*>(prow + kk * 32 + lg * 8);
            float4 b = *reinterpret_cast<const float4*>(prow + kk * 32 + lg * 8 + 4);
            short t[8] = { f2bf(a.x), f2bf(a.y), f2bf(a.z), f2bf(a.w),
                           f2bf(b.x), f2bf(b.y), f2bf(b.z), f2bf(b.w) };
            pa[kk] = *reinterpret_cast<bfrag*>(t);
        }
        __syncthreads();
        #pragma unroll
        for (int ft = 0; ft < 8; ++ft) {
            #pragma unroll
            for (int kk = 0; kk < 2; ++kk) {
                bfrag b = *reinterpret_cast<const bfrag*>(
                    &Xt[ft * 16 + l16][kk * 32 + lg * 8]);
                acc[ft] = __builtin_amdgcn_mfma_f32_16x16x32_bf16(pa[kk], b, acc[ft], 0, 0, 0);
            }
        }
    }
    __syncthreads();
    #pragma unroll
    for (int ft = 0; ft < 8; ++ft)
        #pragma unroll
        for (int r = 0; r < 4; ++r)
            poolS[wid * 16 + lg * 4 + r][ft * 16 + l16] = f2bf(acc[ft][r]);
    __syncthreads();
    bfrag a2[4];
    #pragma unroll
    for (int kk = 0; kk < 4; ++kk)
        a2[kk] = *reinterpret_cast<const bfrag*>(&poolS[wid * 16 + l16][kk * 32 + lg * 8]);
    #pragma unroll
    for (int gt = 0; gt < 8; ++gt) {
        f32x4 o = {0.f, 0.f, 0.f, 0.f};
        #pragma unroll
        for (int kk = 0; kk < 4; ++kk) {
            bfrag b2 = *reinterpret_cast<const bfrag*>(&WtS[gt * 16 + l16][kk * 32 + lg * 8]);
            o = __builtin_amdgcn_mfma_f32_16x16x32_bf16(a2[kk], b2, o, 0, 0, 0);
        }
        #pragma unroll
        for (int r = 0; r < 4; ++r) {
            int n = n0 + wid * 16 + lg * 4 + r;
            outG[((size_t)(bt * NN + n)) * NFG + gt * 16 + l16] = o[r];
        }
    }
}

// ---------------------------------------------------------------------------
extern "C" void kernel_launch(void* const* d_in, const int* in_sizes, int n_in,
                              void* d_out, int out_size, void* d_ws, size_t ws_size,
                              hipStream_t stream) {
    const float* X     = (const float*)d_in[0];
    const float* boxes = (const float*)d_in[1];
    const float* W     = (const float*)d_in[2];
    const float* thw   = (const float*)d_in[3];
    const float* thb   = (const float*)d_in[4];
    const float* phw   = (const float*)d_in[5];
    const float* phb   = (const float*)d_in[6];

    float* outR = (float*)d_out;                       // [256*512][128] f32
    float* rgR  = outR + (size_t)BT * NN * NFG;        // [256*512][512] f32

    const size_t TH = (size_t)BT * NN * NFR * 2;       // 16,777,216 B
    const size_t YT = (size_t)BT * NFG * NN * 2;       // 33,554,432 B
    const size_t WS_NEED = TH * 2 + YT + (size_t)NFG * NFG * 2;   // 67,141,632 B
    if (ws_size >= WS_NEED) {
        char* ws = (char*)d_ws;
        short* thetaS = (short*)(ws);
        short* phiS   = (short*)(ws + TH);
        short* YtG    = (short*)(ws + 2 * TH);
        short* WtB    = (short*)(ws + 2 * TH + YT);
        k_prep <<<64, 256, 0, stream>>>(W, WtB);
        k_projF<<<dim3(8, BT), 256, 0, stream>>>(X, thw, thb, phw, phb, WtB,
                                                 thetaS, phiS, YtG);
        k_fused<<<2048, 256, 0, stream>>>(thetaS, phiS, YtG, boxes, outR, rgR);
    } else {
        short* thetaS = (short*)d_out;
        short* phiS   = thetaS + (size_t)BT * NN * NFR;
        k_proj<<<dim3(8, BT), 256, 0, stream>>>(X, thw, thb, phw, phb, thetaS, phiS);
        k_sim <<<dim3(8, BT), 512, 0, stream>>>(thetaS, phiS, boxes, rgR);
        k_pool<<<dim3(8, BT), 256, 0, stream>>>(rgR, X, W, outR);
    }
}

// Round 8
// 310.834 us; speedup vs baseline: 1.0789x; 1.0789x over previous
//
#include <hip/hip_runtime.h>
#include <hip/hip_bf16.h>

#define NN 512
#define NFG 128
#define NFR 64
#define BT 256

typedef __attribute__((ext_vector_type(8))) short bfrag;   // 8 bf16
typedef __attribute__((ext_vector_type(4))) float f32x4;

__device__ __forceinline__ short f2bf(float f) {
    unsigned u = __float_as_uint(f);
    return (short)((u + 0x7fffu + ((u >> 16) & 1u)) >> 16);
}

// ---------------------------------------------------------------------------
// k_prep: WtB[g][f] = bf16(W[f][g])
__global__ __launch_bounds__(256) void k_prep(const float* __restrict__ W,
                                              short* __restrict__ WtB) {
    int i = blockIdx.x * 256 + threadIdx.x;
    if (i < NFG * NFG) { int f = i >> 7, g = i & 127; WtB[g * NFG + f] = f2bf(W[i]); }
}

// ---------------------------------------------------------------------------
// k_projF: theta = (X@thw^T + thb) * 0.125  (pre-scaled, lossless pow2);
//          phi = X@phw^T + phb ; Yt = (X@W)^T
__global__ __launch_bounds__(256) void k_projF(const float* __restrict__ X,
                                               const float* __restrict__ thw,
                                               const float* __restrict__ thb,
                                               const float* __restrict__ phw,
                                               const float* __restrict__ phb,
                                               const short* __restrict__ WtB,
                                               short* __restrict__ thetaS,
                                               short* __restrict__ phiS,
                                               short* __restrict__ YtG) {
    __shared__ short Xs[64][136];
    __shared__ short wS[2][64][136];
    __shared__ float bS[2][64];
    const int bt = blockIdx.y, n0 = blockIdx.x * 64, tid = threadIdx.x;

    {   // stage X tile (f32 -> bf16)
        int row = tid >> 2, seg = tid & 3;
        const float* src = X + ((size_t)(bt * NN + n0 + row)) * NFG + seg * 32;
        short tmp[32];
        #pragma unroll
        for (int k = 0; k < 8; ++k) {
            float4 v = reinterpret_cast<const float4*>(src)[k];
            tmp[k*4+0] = f2bf(v.x); tmp[k*4+1] = f2bf(v.y);
            tmp[k*4+2] = f2bf(v.z); tmp[k*4+3] = f2bf(v.w);
        }
        #pragma unroll
        for (int k = 0; k < 4; ++k)
            reinterpret_cast<uint4*>(&Xs[row][seg * 32])[k] =
                reinterpret_cast<uint4*>(tmp)[k];
    }
    #pragma unroll
    for (int k = 0; k < 32; ++k) {
        int idx = k * 256 + tid;
        int r = idx >> 7, f = idx & 127;
        wS[0][r][f] = f2bf(thw[idx]);
        wS[1][r][f] = f2bf(phw[idx]);
    }
    if (tid < 64) { bS[0][tid] = thb[tid]; bS[1][tid] = phb[tid]; }
    __syncthreads();

    const int wid = tid >> 6, lane = tid & 63;
    const int l16 = lane & 15, lg = lane >> 4;

    bfrag xa[4];
    #pragma unroll
    for (int kk = 0; kk < 4; ++kk)
        xa[kk] = *reinterpret_cast<const bfrag*>(&Xs[wid * 16 + l16][kk * 32 + lg * 8]);

    for (int pass = 0; pass < 2; ++pass) {
        short* dst = pass ? phiS : thetaS;
        const float sc = pass ? 1.0f : 0.125f;
        #pragma unroll
        for (int c = 0; c < 4; ++c) {
            f32x4 acc = {0.f, 0.f, 0.f, 0.f};
            #pragma unroll
            for (int kk = 0; kk < 4; ++kk) {
                bfrag b = *reinterpret_cast<const bfrag*>(
                    &wS[pass][c * 16 + l16][kk * 32 + lg * 8]);
                acc = __builtin_amdgcn_mfma_f32_16x16x32_bf16(xa[kk], b, acc, 0, 0, 0);
            }
            float bv = bS[pass][c * 16 + l16];
            #pragma unroll
            for (int r = 0; r < 4; ++r) {
                int n = n0 + wid * 16 + lg * 4 + r;
                dst[((size_t)(bt * NN + n)) * NFR + c * 16 + l16] =
                    f2bf((acc[r] + bv) * sc);
            }
        }
    }

    // Yt[g][m] = sum_f Wt[g][f] * X[m][f]
    #pragma unroll
    for (int gi = 0; gi < 2; ++gi) {
        int gs = wid * 2 + gi;
        bfrag wa[4];
        #pragma unroll
        for (int kk = 0; kk < 4; ++kk)
            wa[kk] = *reinterpret_cast<const bfrag*>(
                &WtB[(gs * 16 + l16) * NFG + kk * 32 + lg * 8]);
        #pragma unroll
        for (int ms = 0; ms < 4; ++ms) {
            f32x4 acc = {0.f, 0.f, 0.f, 0.f};
            #pragma unroll
            for (int kk = 0; kk < 4; ++kk) {
                bfrag xb = *reinterpret_cast<const bfrag*>(
                    &Xs[ms * 16 + l16][kk * 32 + lg * 8]);
                acc = __builtin_amdgcn_mfma_f32_16x16x32_bf16(wa[kk], xb, acc, 0, 0, 0);
            }
            #pragma unroll
            for (int r = 0; r < 4; ++r) {
                int g = gs * 16 + lg * 4 + r;
                int m = n0 + ms * 16 + l16;
                YtG[((size_t)(bt * NFG + g)) * NN + m] = f2bf(acc[r]);
            }
        }
    }
}

// ---------------------------------------------------------------------------
// k_fused2: 16-row blocks, 128 threads, S = 16x512 bf16 XOR-swizzled (16 KB).
//   QK (theta pre-scaled) + inline exact mask from boxes + exp -> S bf16
//   -> sum/inv -> rg = S*inv (f32)  -> PV: out = S @ Yt * inv.
//   9 blocks/CU (18 waves), 2 barriers.
__global__ __launch_bounds__(128, 8) void k_fused2(const short* __restrict__ thetaS,
                                                   const short* __restrict__ phiS,
                                                   const short* __restrict__ YtG,
                                                   const float* __restrict__ boxes,
                                                   float* __restrict__ outG,
                                                   float* __restrict__ rgG) {
    __shared__ short S[16 * 512];      // 16,384 B (XOR-swizzled 16B granules)
    __shared__ float invS[16];
    const int bid = blockIdx.x;        // 0..8191
    const int jj = bid >> 3;
    const int bt = (bid & 7) * 32 + (jj >> 5);   // 32 blocks/frame on one XCD
    const int n0 = (jj & 31) * 16;
    const int tid = threadIdx.x;
    const int wid = tid >> 6, lane = tid & 63;
    const int l16 = lane & 15, lg = lane >> 4;
    const int r8 = l16 & 7;
    const size_t fr = (size_t)bt * NN;
    const float THR = __uint_as_float(0x43800001u);   // 256 + 2^-15

    // theta B-frags (already scaled by 1/8 -> MFMA output IS sim)
    bfrag thB0 = *reinterpret_cast<const bfrag*>(&thetaS[(fr + n0 + l16) * NFR + lg * 8]);
    bfrag thB1 = *reinterpret_cast<const bfrag*>(&thetaS[(fr + n0 + l16) * NFR + 32 + lg * 8]);

    // this lane's n-center (bit-exact vs numpy f32 RNE)
    float4 bn = reinterpret_cast<const float4*>(boxes)[fr + n0 + l16];
    const float cnx = __fmul_rn(__fadd_rn(bn.x, bn.z), 0.5f);
    const float cny = __fmul_rn(__fadd_rn(bn.y, bn.w), 0.5f);

    // -------- QK + mask + exp -> S ---------------------------------------
    #pragma unroll
    for (int t = 0; t < 16; ++t) {
        const int mb = wid * 256 + t * 16;
        const short* prow = &phiS[(fr + mb + l16) * NFR + lg * 8];
        bfrag pa0 = *reinterpret_cast<const bfrag*>(prow);
        bfrag pa1 = *reinterpret_cast<const bfrag*>(prow + 32);
        f32x4 acc = {0.f, 0.f, 0.f, 0.f};
        acc = __builtin_amdgcn_mfma_f32_16x16x32_bf16(pa0, thB0, acc, 0, 0, 0);
        acc = __builtin_amdgcn_mfma_f32_16x16x32_bf16(pa1, thB1, acc, 0, 0, 0);
        float e[4];
        #pragma unroll
        for (int r = 0; r < 4; ++r) {
            int m = mb + lg * 4 + r;
            // mask from boxes directly (L1-hot; 16 lanes share each address)
            float4 bm = reinterpret_cast<const float4*>(boxes)[fr + m];
            float cmx = __fmul_rn(__fadd_rn(bm.x, bm.z), 0.5f);
            float cmy = __fmul_rn(__fadd_rn(bm.y, bm.w), 0.5f);
            float dx = __fsub_rn(cnx, cmx), dy = __fsub_rn(cny, cmy);
            float d2 = __fadd_rn(__fmul_rn(dx, dx), __fmul_rn(dy, dy));
            e[r] = (d2 > THR) ? 0.f : __expf(acc[r]);   // no-max-sub: |sim|<~2
        }
        unsigned q0, q1;
        asm("v_cvt_pk_bf16_f32 %0, %1, %2" : "=v"(q0) : "v"(e[0]), "v"(e[1]));
        asm("v_cvt_pk_bf16_f32 %0, %1, %2" : "=v"(q1) : "v"(e[2]), "v"(e[3]));
        uint2 qq; qq.x = q0; qq.y = q1;
        const int g = wid * 32 + t * 2 + (lg >> 1);     // 16B granule index
        *reinterpret_cast<uint2*>(
            &S[(l16 << 9) + ((g ^ r8) << 3) + ((lg & 1) << 2)]) = qq;
    }
    __syncthreads();

    // -------- sum -> inv -> rg = S*inv (f32) ------------------------------
    {
        const int g16 = tid >> 4, li = tid & 15;
        #pragma unroll
        for (int rr = 0; rr < 2; ++rr) {
            const int row = g16 * 2 + rr;
            const int rw8 = row & 7;
            float sm = 0.f;
            #pragma unroll
            for (int c = 0; c < 4; ++c) {
                const uint4 ch = *reinterpret_cast<const uint4*>(
                    &S[(row << 9) + (((li * 4 + c) ^ rw8) << 3)]);
                float s0 = __uint_as_float(ch.x << 16) + __uint_as_float(ch.x & 0xffff0000u);
                float s1 = __uint_as_float(ch.y << 16) + __uint_as_float(ch.y & 0xffff0000u);
                float s2 = __uint_as_float(ch.z << 16) + __uint_as_float(ch.z & 0xffff0000u);
                float s3 = __uint_as_float(ch.w << 16) + __uint_as_float(ch.w & 0xffff0000u);
                sm += (s0 + s1) + (s2 + s3);
            }
            sm += __shfl_xor(sm, 1);
            sm += __shfl_xor(sm, 2);
            sm += __shfl_xor(sm, 4);
            sm += __shfl_xor(sm, 8);
            const float inv = 1.0f / sm;
            if (li == 0) invS[row] = inv;
            float* rp = rgG + (fr + n0 + row) * NN;
            #pragma unroll
            for (int c = 0; c < 4; ++c) {
                const int gl = li * 4 + c;
                const uint4 ch = *reinterpret_cast<const uint4*>(
                    &S[(row << 9) + ((gl ^ rw8) << 3)]);
                float4 aa, bb;
                aa.x = __uint_as_float(ch.x << 16) * inv;
                aa.y = __uint_as_float(ch.x & 0xffff0000u) * inv;
                aa.z = __uint_as_float(ch.y << 16) * inv;
                aa.w = __uint_as_float(ch.y & 0xffff0000u) * inv;
                bb.x = __uint_as_float(ch.z << 16) * inv;
                bb.y = __uint_as_float(ch.z & 0xffff0000u) * inv;
                bb.z = __uint_as_float(ch.w << 16) * inv;
                bb.w = __uint_as_float(ch.w & 0xffff0000u) * inv;
                *reinterpret_cast<float4*>(rp + gl * 8)     = aa;
                *reinterpret_cast<float4*>(rp + gl * 8 + 4) = bb;
            }
        }
    }
    __syncthreads();

    // -------- PV: out = S @ Yt * inv  (direct global Yt B-frags) ----------
    f32x4 pool[4];
    #pragma unroll
    for (int gi = 0; gi < 4; ++gi) pool[gi] = f32x4{0.f, 0.f, 0.f, 0.f};
    const short* ytb = &YtG[(size_t)bt * NFG * NN + (size_t)wid * 64 * NN];

    #pragma unroll 4
    for (int c = 0; c < 16; ++c) {
        bfrag pa = *reinterpret_cast<const bfrag*>(
            &S[(l16 << 9) + (((c * 4 + lg) ^ r8) << 3)]);
        #pragma unroll
        for (int gi = 0; gi < 4; ++gi) {
            bfrag yb = *reinterpret_cast<const bfrag*>(
                &ytb[(gi * 16 + l16) * NN + c * 32 + lg * 8]);
            pool[gi] = __builtin_amdgcn_mfma_f32_16x16x32_bf16(pa, yb, pool[gi], 0, 0, 0);
        }
    }
    float iv[4];
    #pragma unroll
    for (int r = 0; r < 4; ++r) iv[r] = invS[lg * 4 + r];
    #pragma unroll
    for (int gi = 0; gi < 4; ++gi) {
        #pragma unroll
        for (int r = 0; r < 4; ++r) {
            outG[(fr + n0 + lg * 4 + r) * NFG + wid * 64 + gi * 16 + l16]
                = pool[gi][r] * iv[r];
        }
    }
}

// ---------------------------------------------------------------------------
// Fallback path (proven round-4 kernels), used only if ws is too small.
__global__ __launch_bounds__(256) void k_proj(const float* __restrict__ X,
                                              const float* __restrict__ thw,
                                              const float* __restrict__ thb,
                                              const float* __restrict__ phw,
                                              const float* __restrict__ phb,
                                              short* __restrict__ thetaS,
                                              short* __restrict__ phiS) {
    __shared__ short Xs[64][136];
    __shared__ short wS[2][64][136];
    __shared__ float bS[2][64];
    const int bt = blockIdx.y, n0 = blockIdx.x * 64, tid = threadIdx.x;
    {
        int row = tid >> 2, seg = tid & 3;
        const float* src = X + ((size_t)(bt * NN + n0 + row)) * NFG + seg * 32;
        short tmp[32];
        #pragma unroll
        for (int k = 0; k < 8; ++k) {
            float4 v = reinterpret_cast<const float4*>(src)[k];
            tmp[k*4+0] = f2bf(v.x); tmp[k*4+1] = f2bf(v.y);
            tmp[k*4+2] = f2bf(v.z); tmp[k*4+3] = f2bf(v.w);
        }
        #pragma unroll
        for (int k = 0; k < 4; ++k)
            reinterpret_cast<uint4*>(&Xs[row][seg * 32])[k] =
                reinterpret_cast<uint4*>(tmp)[k];
    }
    #pragma unroll
    for (int k = 0; k < 32; ++k) {
        int idx = k * 256 + tid;
        int r = idx >> 7, f = idx & 127;
        wS[0][r][f] = f2bf(thw[idx]);
        wS[1][r][f] = f2bf(phw[idx]);
    }
    if (tid < 64) { bS[0][tid] = thb[tid]; bS[1][tid] = phb[tid]; }
    __syncthreads();
    const int wid = tid >> 6, lane = tid & 63;
    const int l16 = lane & 15, lg = lane >> 4;
    bfrag xa[4];
    #pragma unroll
    for (int kk = 0; kk < 4; ++kk)
        xa[kk] = *reinterpret_cast<const bfrag*>(&Xs[wid * 16 + l16][kk * 32 + lg * 8]);
    for (int pass = 0; pass < 2; ++pass) {
        short* dst = pass ? phiS : thetaS;
        #pragma unroll
        for (int c = 0; c < 4; ++c) {
            f32x4 acc = {0.f, 0.f, 0.f, 0.f};
            #pragma unroll
            for (int kk = 0; kk < 4; ++kk) {
                bfrag b = *reinterpret_cast<const bfrag*>(
                    &wS[pass][c * 16 + l16][kk * 32 + lg * 8]);
                acc = __builtin_amdgcn_mfma_f32_16x16x32_bf16(xa[kk], b, acc, 0, 0, 0);
            }
            float bv = bS[pass][c * 16 + l16];
            #pragma unroll
            for (int r = 0; r < 4; ++r) {
                int n = n0 + wid * 16 + lg * 4 + r;
                dst[((size_t)(bt * NN + n)) * NFR + c * 16 + l16] = f2bf(acc[r] + bv);
            }
        }
    }
}

__global__ __launch_bounds__(512) void k_sim(const short* __restrict__ thetaS,
                                             const short* __restrict__ phiS,
                                             const float* __restrict__ boxes,
                                             float* __restrict__ rgG) {
    __shared__ float S[64][516];
    __shared__ float cxs[NN], cys[NN];
    const int bt = blockIdx.y, n0 = blockIdx.x * 64, tid = threadIdx.x;
    const int wid = tid >> 6, lane = tid & 63;
    const int l16 = lane & 15, lg = lane >> 4;
    const int rsub = wid & 3, ch = wid >> 2;
    {
        float4 b = reinterpret_cast<const float4*>(boxes)[bt * NN + tid];
        cxs[tid] = __fmul_rn(__fadd_rn(b.x, b.z), 0.5f);
        cys[tid] = __fmul_rn(__fadd_rn(b.y, b.w), 0.5f);
    }
    bfrag thA[2];
    #pragma unroll
    for (int kk = 0; kk < 2; ++kk)
        thA[kk] = *reinterpret_cast<const bfrag*>(
            &thetaS[((size_t)(bt * NN + n0 + rsub * 16 + l16)) * NFR + kk * 32 + lg * 8]);
    __syncthreads();
    #pragma unroll 1
    for (int mt = 0; mt < 8; ++mt) {
        int m0 = mt * 64;
        #pragma unroll
        for (int ci = 0; ci < 2; ++ci) {
            int cs = ch * 2 + ci;
            int m = m0 + cs * 16 + l16;
            f32x4 acc = {0.f, 0.f, 0.f, 0.f};
            #pragma unroll
            for (int kk = 0; kk < 2; ++kk) {
                bfrag pb = *reinterpret_cast<const bfrag*>(
                    &phiS[((size_t)(bt * NN + m)) * NFR + kk * 32 + lg * 8]);
                acc = __builtin_amdgcn_mfma_f32_16x16x32_bf16(thA[kk], pb, acc, 0, 0, 0);
            }
            float cxm = cxs[m], cym = cys[m];
            #pragma unroll
            for (int r = 0; r < 4; ++r) {
                int nl = rsub * 16 + lg * 4 + r;
                float dx = __fsub_rn(cxs[n0 + nl], cxm);
                float dy = __fsub_rn(cys[n0 + nl], cym);
                float d2 = __fadd_rn(__fmul_rn(dx, dx), __fmul_rn(dy, dy));
                S[nl][m] = (d2 > __uint_as_float(0x43800001u))
                               ? -__builtin_inff() : acc[r] * 0.125f;
            }
        }
    }
    __syncthreads();
    {
        int row = tid >> 3, j = tid & 7;
        float* Sp = &S[row][j * 64];
        float mx = -__builtin_inff();
        #pragma unroll
        for (int k = 0; k < 16; ++k) {
            float4 v = *reinterpret_cast<float4*>(Sp + k * 4);
            mx = fmaxf(mx, fmaxf(fmaxf(v.x, v.y), fmaxf(v.z, v.w)));
        }
        mx = fmaxf(mx, __shfl_xor(mx, 1));
        mx = fmaxf(mx, __shfl_xor(mx, 2));
        mx = fmaxf(mx, __shfl_xor(mx, 4));
        float sm = 0.f;
        #pragma unroll
        for (int k = 0; k < 16; ++k) {
            float4 v = *reinterpret_cast<float4*>(Sp + k * 4);
            v.x = __expf(v.x - mx); v.y = __expf(v.y - mx);
            v.z = __expf(v.z - mx); v.w = __expf(v.w - mx);
            sm += (v.x + v.y) + (v.z + v.w);
            *reinterpret_cast<float4*>(Sp + k * 4) = v;
        }
        sm += __shfl_xor(sm, 1);
        sm += __shfl_xor(sm, 2);
        sm += __shfl_xor(sm, 4);
        float inv = 1.0f / sm;
        float* rp = rgG + ((size_t)(bt * NN) + n0 + row) * NN + j * 64;
        #pragma unroll
        for (int k = 0; k < 16; ++k) {
            float4 a = *reinterpret_cast<float4*>(Sp + k * 4);
            a.x *= inv; a.y *= inv; a.z *= inv; a.w *= inv;
            *reinterpret_cast<float4*>(rp + k * 4) = a;
        }
    }
}

__global__ __launch_bounds__(256) void k_pool(const float* __restrict__ rgG,
                                              const float* __restrict__ X,
                                              const float* __restrict__ W,
                                              float* __restrict__ outG) {
    __shared__ short Xt[128][72];
    __shared__ short poolS[64][136];
    __shared__ short WtS[128][136];
    const int bt = blockIdx.y, n0 = blockIdx.x * 64, tid = threadIdx.x;
    const int wid = tid >> 6, lane = tid & 63;
    const int l16 = lane & 15, lg = lane >> 4;
    #pragma unroll
    for (int k = 0; k < 64; ++k) {
        int idx = k * 256 + tid;
        int f = idx >> 7, g = idx & 127;
        WtS[g][f] = f2bf(W[idx]);
    }
    f32x4 acc[8];
    #pragma unroll
    for (int ft = 0; ft < 8; ++ft) acc[ft] = f32x4{0.f, 0.f, 0.f, 0.f};
    #pragma unroll 1
    for (int mt = 0; mt < 8; ++mt) {
        __syncthreads();
        {
            int m = tid >> 2, seg = tid & 3;
            const float* src = X + ((size_t)(bt * NN + mt * 64 + m)) * NFG + seg * 32;
            #pragma unroll
            for (int k = 0; k < 8; ++k) {
                float4 v = reinterpret_cast<const float4*>(src)[k];
                int f = seg * 32 + k * 4;
                Xt[f + 0][m] = f2bf(v.x); Xt[f + 1][m] = f2bf(v.y);
                Xt[f + 2][m] = f2bf(v.z); Xt[f + 3][m] = f2bf(v.w);
            }
        }
        bfrag pa[2];
        const float* prow = rgG + ((size_t)(bt * NN + n0 + wid * 16 + l16)) * NN + mt * 64;
        #pragma unroll
        for (int kk = 0; kk < 2; ++kk) {
            float4 a = *reinterpret_cast<const float4*>(prow + kk * 32 + lg * 8);
            float4 b = *reinterpret_cast<const float4*>(prow + kk * 32 + lg * 8 + 4);
            short t[8] = { f2bf(a.x), f2bf(a.y), f2bf(a.z), f2bf(a.w),
                           f2bf(b.x), f2bf(b.y), f2bf(b.z), f2bf(b.w) };
            pa[kk] = *reinterpret_cast<bfrag*>(t);
        }
        __syncthreads();
        #pragma unroll
        for (int ft = 0; ft < 8; ++ft) {
            #pragma unroll
            for (int kk = 0; kk < 2; ++kk) {
                bfrag b = *reinterpret_cast<const bfrag*>(
                    &Xt[ft * 16 + l16][kk * 32 + lg * 8]);
                acc[ft] = __builtin_amdgcn_mfma_f32_16x16x32_bf16(pa[kk], b, acc[ft], 0, 0, 0);
            }
        }
    }
    __syncthreads();
    #pragma unroll
    for (int ft = 0; ft < 8; ++ft)
        #pragma unroll
        for (int r = 0; r < 4; ++r)
            poolS[wid * 16 + lg * 4 + r][ft * 16 + l16] = f2bf(acc[ft][r]);
    __syncthreads();
    bfrag a2[4];
    #pragma unroll
    for (int kk = 0; kk < 4; ++kk)
        a2[kk] = *reinterpret_cast<const bfrag*>(&poolS[wid * 16 + l16][kk * 32 + lg * 8]);
    #pragma unroll
    for (int gt = 0; gt < 8; ++gt) {
        f32x4 o = {0.f, 0.f, 0.f, 0.f};
        #pragma unroll
        for (int kk = 0; kk < 4; ++kk) {
            bfrag b2 = *reinterpret_cast<const bfrag*>(&WtS[gt * 16 + l16][kk * 32 + lg * 8]);
            o = __builtin_amdgcn_mfma_f32_16x16x32_bf16(a2[kk], b2, o, 0, 0, 0);
        }
        #pragma unroll
        for (int r = 0; r < 4; ++r) {
            int n = n0 + wid * 16 + lg * 4 + r;
            outG[((size_t)(bt * NN + n)) * NFG + gt * 16 + l16] = o[r];
        }
    }
}

// ---------------------------------------------------------------------------
extern "C" void kernel_launch(void* const* d_in, const int* in_sizes, int n_in,
                              void* d_out, int out_size, void* d_ws, size_t ws_size,
                              hipStream_t stream) {
    const float* X     = (const float*)d_in[0];
    const float* boxes = (const float*)d_in[1];
    const float* W     = (const float*)d_in[2];
    const float* thw   = (const float*)d_in[3];
    const float* thb   = (const float*)d_in[4];
    const float* phw   = (const float*)d_in[5];
    const float* phb   = (const float*)d_in[6];

    float* outR = (float*)d_out;                       // [256*512][128] f32
    float* rgR  = outR + (size_t)BT * NN * NFG;        // [256*512][512] f32

    const size_t TH = (size_t)BT * NN * NFR * 2;       // 16,777,216 B
    const size_t YT = (size_t)BT * NFG * NN * 2;       // 33,554,432 B
    const size_t WS_NEED = TH * 2 + YT + (size_t)NFG * NFG * 2;   // 67,141,632 B
    if (ws_size >= WS_NEED) {
        char* ws = (char*)d_ws;
        short* thetaS = (short*)(ws);
        short* phiS   = (short*)(ws + TH);
        short* YtG    = (short*)(ws + 2 * TH);
        short* WtB    = (short*)(ws + 2 * TH + YT);
        k_prep  <<<64, 256, 0, stream>>>(W, WtB);
        k_projF <<<dim3(8, BT), 256, 0, stream>>>(X, thw, thb, phw, phb, WtB,
                                                  thetaS, phiS, YtG);
        k_fused2<<<8192, 128, 0, stream>>>(thetaS, phiS, YtG, boxes, outR, rgR);
    } else {
        short* thetaS = (short*)d_out;
        short* phiS   = thetaS + (size_t)BT * NN * NFR;
        k_proj<<<dim3(8, BT), 256, 0, stream>>>(X, thw, thb, phw, phb, thetaS, phiS);
        k_sim <<<dim3(8, BT), 512, 0, stream>>>(thetaS, phiS, boxes, rgR);
        k_pool<<<dim3(8, BT), 256, 0, stream>>>(rgR, X, W, outR);
    }
}

// Round 9
// 214.123 us; speedup vs baseline: 1.5661x; 1.4517x over previous
//
#include <hip/hip_runtime.h>
#include <hip/hip_bf16.h>

#define NN 512
#define NFG 128
#define NFR 64
#define BT 256

typedef __attribute__((ext_vector_type(8))) short bfrag;   // 8 bf16
typedef __attribute__((ext_vector_type(4))) float f32x4;

__device__ __forceinline__ short f2bf(float f) {
    unsigned u = __float_as_uint(f);
    return (short)((u + 0x7fffu + ((u >> 16) & 1u)) >> 16);
}

// ---------------------------------------------------------------------------
// k_prep: WtB[g][f] = bf16(W[f][g])
__global__ __launch_bounds__(256) void k_prep(const float* __restrict__ W,
                                              short* __restrict__ WtB) {
    int i = blockIdx.x * 256 + threadIdx.x;
    if (i < NFG * NFG) { int f = i >> 7, g = i & 127; WtB[g * NFG + f] = f2bf(W[i]); }
}

// ---------------------------------------------------------------------------
// k_projF: theta = (X@thw^T + thb) * 0.125 ; phi = X@phw^T + phb ;
//          Yt tiled: Yt2[c][g][mm] = (X@W)[m][g], c=m>>5, mm=m&31
__global__ __launch_bounds__(256) void k_projF(const float* __restrict__ X,
                                               const float* __restrict__ thw,
                                               const float* __restrict__ thb,
                                               const float* __restrict__ phw,
                                               const float* __restrict__ phb,
                                               const short* __restrict__ WtB,
                                               short* __restrict__ thetaS,
                                               short* __restrict__ phiS,
                                               short* __restrict__ YtG) {
    __shared__ short Xs[64][136];
    __shared__ short wS[2][64][136];
    __shared__ float bS[2][64];
    const int bt = blockIdx.y, n0 = blockIdx.x * 64, tid = threadIdx.x;

    {   // stage X tile (f32 -> bf16)
        int row = tid >> 2, seg = tid & 3;
        const float* src = X + ((size_t)(bt * NN + n0 + row)) * NFG + seg * 32;
        short tmp[32];
        #pragma unroll
        for (int k = 0; k < 8; ++k) {
            float4 v = reinterpret_cast<const float4*>(src)[k];
            tmp[k*4+0] = f2bf(v.x); tmp[k*4+1] = f2bf(v.y);
            tmp[k*4+2] = f2bf(v.z); tmp[k*4+3] = f2bf(v.w);
        }
        #pragma unroll
        for (int k = 0; k < 4; ++k)
            reinterpret_cast<uint4*>(&Xs[row][seg * 32])[k] =
                reinterpret_cast<uint4*>(tmp)[k];
    }
    #pragma unroll
    for (int k = 0; k < 32; ++k) {
        int idx = k * 256 + tid;
        int r = idx >> 7, f = idx & 127;
        wS[0][r][f] = f2bf(thw[idx]);
        wS[1][r][f] = f2bf(phw[idx]);
    }
    if (tid < 64) { bS[0][tid] = thb[tid]; bS[1][tid] = phb[tid]; }
    __syncthreads();

    const int wid = tid >> 6, lane = tid & 63;
    const int l16 = lane & 15, lg = lane >> 4;

    bfrag xa[4];
    #pragma unroll
    for (int kk = 0; kk < 4; ++kk)
        xa[kk] = *reinterpret_cast<const bfrag*>(&Xs[wid * 16 + l16][kk * 32 + lg * 8]);

    for (int pass = 0; pass < 2; ++pass) {
        short* dst = pass ? phiS : thetaS;
        const float sc = pass ? 1.0f : 0.125f;
        #pragma unroll
        for (int c = 0; c < 4; ++c) {
            f32x4 acc = {0.f, 0.f, 0.f, 0.f};
            #pragma unroll
            for (int kk = 0; kk < 4; ++kk) {
                bfrag b = *reinterpret_cast<const bfrag*>(
                    &wS[pass][c * 16 + l16][kk * 32 + lg * 8]);
                acc = __builtin_amdgcn_mfma_f32_16x16x32_bf16(xa[kk], b, acc, 0, 0, 0);
            }
            float bv = bS[pass][c * 16 + l16];
            #pragma unroll
            for (int r = 0; r < 4; ++r) {
                int n = n0 + wid * 16 + lg * 4 + r;
                dst[((size_t)(bt * NN + n)) * NFR + c * 16 + l16] =
                    f2bf((acc[r] + bv) * sc);
            }
        }
    }

    // Yt tiled store: addr = bt*65536 + (c*128 + g)*32 + mm
    const size_t ybase = (size_t)bt * NFG * NN;
    #pragma unroll
    for (int gi = 0; gi < 2; ++gi) {
        int gs = wid * 2 + gi;
        bfrag wa[4];
        #pragma unroll
        for (int kk = 0; kk < 4; ++kk)
            wa[kk] = *reinterpret_cast<const bfrag*>(
                &WtB[(gs * 16 + l16) * NFG + kk * 32 + lg * 8]);
        #pragma unroll
        for (int ms = 0; ms < 4; ++ms) {
            f32x4 acc = {0.f, 0.f, 0.f, 0.f};
            #pragma unroll
            for (int kk = 0; kk < 4; ++kk) {
                bfrag xb = *reinterpret_cast<const bfrag*>(
                    &Xs[ms * 16 + l16][kk * 32 + lg * 8]);
                acc = __builtin_amdgcn_mfma_f32_16x16x32_bf16(wa[kk], xb, acc, 0, 0, 0);
            }
            #pragma unroll
            for (int r = 0; r < 4; ++r) {
                int g = gs * 16 + lg * 4 + r;
                int m = n0 + ms * 16 + l16;
                YtG[ybase + (size_t)((m >> 5) * NFG + g) * 32 + (m & 31)] = f2bf(acc[r]);
            }
        }
    }
}

// ---------------------------------------------------------------------------
// k_fused2: 16-row blocks, 128 threads, S = 16x512 bf16 XOR-swizzled (16 KB).
//   centers in LDS -> QK (theta pre-scaled) + exact mask + exp -> S bf16
//   -> sum/inv -> rg coalesced 512B runs -> PV from tiled Yt (1KB wave runs).
__global__ __launch_bounds__(128, 6) void k_fused2(const short* __restrict__ thetaS,
                                                   const short* __restrict__ phiS,
                                                   const short* __restrict__ YtG,
                                                   const float* __restrict__ boxes,
                                                   float* __restrict__ outG,
                                                   float* __restrict__ rgG) {
    __shared__ short S[16 * 512];      // 16,384 B (XOR-swizzled 16B granules)
    __shared__ float2 c2[NN];          //  4,096 B
    __shared__ float invS[16];
    const int bid = blockIdx.x;        // 0..8191
    const int jj = bid >> 3;
    const int bt = (bid & 7) * 32 + (jj >> 5);   // 32 blocks/frame on one XCD
    const int n0 = (jj & 31) * 16;
    const int tid = threadIdx.x;
    const int wid = tid >> 6, lane = tid & 63;
    const int l16 = lane & 15, lg = lane >> 4;
    const int r8 = l16 & 7;
    const size_t fr = (size_t)bt * NN;
    const float THR = __uint_as_float(0x43800001u);   // 256 + 2^-15

    {   // centers once per block, coalesced (bit-exact vs numpy f32 RNE)
        #pragma unroll
        for (int k = 0; k < 4; ++k) {
            int row = k * 128 + tid;
            float4 b = reinterpret_cast<const float4*>(boxes)[fr + row];
            c2[row] = make_float2(__fmul_rn(__fadd_rn(b.x, b.z), 0.5f),
                                  __fmul_rn(__fadd_rn(b.y, b.w), 0.5f));
        }
    }

    // theta B-frags (already scaled by 1/8 -> MFMA output IS sim)
    bfrag thB0 = *reinterpret_cast<const bfrag*>(&thetaS[(fr + n0 + l16) * NFR + lg * 8]);
    bfrag thB1 = *reinterpret_cast<const bfrag*>(&thetaS[(fr + n0 + l16) * NFR + 32 + lg * 8]);
    __syncthreads();

    const float2 cn = c2[n0 + l16];

    // -------- QK + mask + exp -> S ---------------------------------------
    #pragma unroll
    for (int t = 0; t < 16; ++t) {
        const int mb = wid * 256 + t * 16;
        const short* prow = &phiS[(fr + mb + l16) * NFR + lg * 8];
        bfrag pa0 = *reinterpret_cast<const bfrag*>(prow);
        bfrag pa1 = *reinterpret_cast<const bfrag*>(prow + 32);
        f32x4 acc = {0.f, 0.f, 0.f, 0.f};
        acc = __builtin_amdgcn_mfma_f32_16x16x32_bf16(pa0, thB0, acc, 0, 0, 0);
        acc = __builtin_amdgcn_mfma_f32_16x16x32_bf16(pa1, thB1, acc, 0, 0, 0);
        float e[4];
        #pragma unroll
        for (int r = 0; r < 4; ++r) {
            int m = mb + lg * 4 + r;
            float2 cm = c2[m];
            // masked <=> sqrt_RNE(d2) > 16.0f <=> d2 > 256+2^-15
            float dx = __fsub_rn(cn.x, cm.x), dy = __fsub_rn(cn.y, cm.y);
            float d2 = __fadd_rn(__fmul_rn(dx, dx), __fmul_rn(dy, dy));
            e[r] = (d2 > THR) ? 0.f : __expf(acc[r]);   // no-max-sub: |sim|<~2
        }
        unsigned q0, q1;
        asm("v_cvt_pk_bf16_f32 %0, %1, %2" : "=v"(q0) : "v"(e[0]), "v"(e[1]));
        asm("v_cvt_pk_bf16_f32 %0, %1, %2" : "=v"(q1) : "v"(e[2]), "v"(e[3]));
        uint2 qq; qq.x = q0; qq.y = q1;
        const int g = wid * 32 + t * 2 + (lg >> 1);     // 16B granule index
        *reinterpret_cast<uint2*>(
            &S[(l16 << 9) + ((g ^ r8) << 3) + ((lg & 1) << 2)]) = qq;
    }
    __syncthreads();

    // -------- sum -> inv -> rg (coalesced 512B runs per 16-lane group) ----
    {
        const int g16 = tid >> 4, li = tid & 15;
        #pragma unroll
        for (int rr = 0; rr < 2; ++rr) {
            const int row = g16 * 2 + rr;
            const int rw8 = row & 7;
            float sm = 0.f;
            #pragma unroll
            for (int c = 0; c < 4; ++c) {
                const uint4 ch = *reinterpret_cast<const uint4*>(
                    &S[(row << 9) + (((c * 16 + li) ^ rw8) << 3)]);
                float s0 = __uint_as_float(ch.x << 16) + __uint_as_float(ch.x & 0xffff0000u);
                float s1 = __uint_as_float(ch.y << 16) + __uint_as_float(ch.y & 0xffff0000u);
                float s2 = __uint_as_float(ch.z << 16) + __uint_as_float(ch.z & 0xffff0000u);
                float s3 = __uint_as_float(ch.w << 16) + __uint_as_float(ch.w & 0xffff0000u);
                sm += (s0 + s1) + (s2 + s3);
            }
            sm += __shfl_xor(sm, 1);
            sm += __shfl_xor(sm, 2);
            sm += __shfl_xor(sm, 4);
            sm += __shfl_xor(sm, 8);
            const float inv = 1.0f / sm;
            if (li == 0) invS[row] = inv;
            float* rp = rgG + (fr + n0 + row) * NN;
            #pragma unroll
            for (int c = 0; c < 4; ++c) {
                const int gl = c * 16 + li;            // lanes -> contiguous granules
                const uint4 ch = *reinterpret_cast<const uint4*>(
                    &S[(row << 9) + ((gl ^ rw8) << 3)]);
                float4 aa, bb;
                aa.x = __uint_as_float(ch.x << 16) * inv;
                aa.y = __uint_as_float(ch.x & 0xffff0000u) * inv;
                aa.z = __uint_as_float(ch.y << 16) * inv;
                aa.w = __uint_as_float(ch.y & 0xffff0000u) * inv;
                bb.x = __uint_as_float(ch.z << 16) * inv;
                bb.y = __uint_as_float(ch.z & 0xffff0000u) * inv;
                bb.z = __uint_as_float(ch.w << 16) * inv;
                bb.w = __uint_as_float(ch.w & 0xffff0000u) * inv;
                *reinterpret_cast<float4*>(rp + gl * 8)     = aa;
                *reinterpret_cast<float4*>(rp + gl * 8 + 4) = bb;
            }
        }
    }
    __syncthreads();

    // -------- PV: out = S @ Yt * inv  (tiled Yt: wave reads 1KB runs) -----
    f32x4 pool[4];
    #pragma unroll
    for (int gi = 0; gi < 4; ++gi) pool[gi] = f32x4{0.f, 0.f, 0.f, 0.f};
    const short* ytb = &YtG[(size_t)bt * NFG * NN];

    #pragma unroll 4
    for (int c = 0; c < 16; ++c) {
        bfrag pa = *reinterpret_cast<const bfrag*>(
            &S[(l16 << 9) + (((c * 4 + lg) ^ r8) << 3)]);
        #pragma unroll
        for (int gi = 0; gi < 4; ++gi) {
            const int g = wid * 64 + gi * 16 + l16;
            bfrag yb = *reinterpret_cast<const bfrag*>(
                &ytb[(size_t)(c * NFG + g) * 32 + lg * 8]);
            pool[gi] = __builtin_amdgcn_mfma_f32_16x16x32_bf16(pa, yb, pool[gi], 0, 0, 0);
        }
    }
    float iv[4];
    #pragma unroll
    for (int r = 0; r < 4; ++r) iv[r] = invS[lg * 4 + r];
    #pragma unroll
    for (int gi = 0; gi < 4; ++gi) {
        #pragma unroll
        for (int r = 0; r < 4; ++r) {
            outG[(fr + n0 + lg * 4 + r) * NFG + wid * 64 + gi * 16 + l16]
                = pool[gi][r] * iv[r];
        }
    }
}

// ---------------------------------------------------------------------------
// Fallback path (proven round-4 kernels), used only if ws is too small.
__global__ __launch_bounds__(256) void k_proj(const float* __restrict__ X,
                                              const float* __restrict__ thw,
                                              const float* __restrict__ thb,
                                              const float* __restrict__ phw,
                                              const float* __restrict__ phb,
                                              short* __restrict__ thetaS,
                                              short* __restrict__ phiS) {
    __shared__ short Xs[64][136];
    __shared__ short wS[2][64][136];
    __shared__ float bS[2][64];
    const int bt = blockIdx.y, n0 = blockIdx.x * 64, tid = threadIdx.x;
    {
        int row = tid >> 2, seg = tid & 3;
        const float* src = X + ((size_t)(bt * NN + n0 + row)) * NFG + seg * 32;
        short tmp[32];
        #pragma unroll
        for (int k = 0; k < 8; ++k) {
            float4 v = reinterpret_cast<const float4*>(src)[k];
            tmp[k*4+0] = f2bf(v.x); tmp[k*4+1] = f2bf(v.y);
            tmp[k*4+2] = f2bf(v.z); tmp[k*4+3] = f2bf(v.w);
        }
        #pragma unroll
        for (int k = 0; k < 4; ++k)
            reinterpret_cast<uint4*>(&Xs[row][seg * 32])[k] =
                reinterpret_cast<uint4*>(tmp)[k];
    }
    #pragma unroll
    for (int k = 0; k < 32; ++k) {
        int idx = k * 256 + tid;
        int r = idx >> 7, f = idx & 127;
        wS[0][r][f] = f2bf(thw[idx]);
        wS[1][r][f] = f2bf(phw[idx]);
    }
    if (tid < 64) { bS[0][tid] = thb[tid]; bS[1][tid] = phb[tid]; }
    __syncthreads();
    const int wid = tid >> 6, lane = tid & 63;
    const int l16 = lane & 15, lg = lane >> 4;
    bfrag xa[4];
    #pragma unroll
    for (int kk = 0; kk < 4; ++kk)
        xa[kk] = *reinterpret_cast<const bfrag*>(&Xs[wid * 16 + l16][kk * 32 + lg * 8]);
    for (int pass = 0; pass < 2; ++pass) {
        short* dst = pass ? phiS : thetaS;
        #pragma unroll
        for (int c = 0; c < 4; ++c) {
            f32x4 acc = {0.f, 0.f, 0.f, 0.f};
            #pragma unroll
            for (int kk = 0; kk < 4; ++kk) {
                bfrag b = *reinterpret_cast<const bfrag*>(
                    &wS[pass][c * 16 + l16][kk * 32 + lg * 8]);
                acc = __builtin_amdgcn_mfma_f32_16x16x32_bf16(xa[kk], b, acc, 0, 0, 0);
            }
            float bv = bS[pass][c * 16 + l16];
            #pragma unroll
            for (int r = 0; r < 4; ++r) {
                int n = n0 + wid * 16 + lg * 4 + r;
                dst[((size_t)(bt * NN + n)) * NFR + c * 16 + l16] = f2bf(acc[r] + bv);
            }
        }
    }
}

__global__ __launch_bounds__(512) void k_sim(const short* __restrict__ thetaS,
                                             const short* __restrict__ phiS,
                                             const float* __restrict__ boxes,
                                             float* __restrict__ rgG) {
    __shared__ float S[64][516];
    __shared__ float cxs[NN], cys[NN];
    const int bt = blockIdx.y, n0 = blockIdx.x * 64, tid = threadIdx.x;
    const int wid = tid >> 6, lane = tid & 63;
    const int l16 = lane & 15, lg = lane >> 4;
    const int rsub = wid & 3, ch = wid >> 2;
    {
        float4 b = reinterpret_cast<const float4*>(boxes)[bt * NN + tid];
        cxs[tid] = __fmul_rn(__fadd_rn(b.x, b.z), 0.5f);
        cys[tid] = __fmul_rn(__fadd_rn(b.y, b.w), 0.5f);
    }
    bfrag thA[2];
    #pragma unroll
    for (int kk = 0; kk < 2; ++kk)
        thA[kk] = *reinterpret_cast<const bfrag*>(
            &thetaS[((size_t)(bt * NN + n0 + rsub * 16 + l16)) * NFR + kk * 32 + lg * 8]);
    __syncthreads();
    #pragma unroll 1
    for (int mt = 0; mt < 8; ++mt) {
        int m0 = mt * 64;
        #pragma unroll
        for (int ci = 0; ci < 2; ++ci) {
            int cs = ch * 2 + ci;
            int m = m0 + cs * 16 + l16;
            f32x4 acc = {0.f, 0.f, 0.f, 0.f};
            #pragma unroll
            for (int kk = 0; kk < 2; ++kk) {
                bfrag pb = *reinterpret_cast<const bfrag*>(
                    &phiS[((size_t)(bt * NN + m)) * NFR + kk * 32 + lg * 8]);
                acc = __builtin_amdgcn_mfma_f32_16x16x32_bf16(thA[kk], pb, acc, 0, 0, 0);
            }
            float cxm = cxs[m], cym = cys[m];
            #pragma unroll
            for (int r = 0; r < 4; ++r) {
                int nl = rsub * 16 + lg * 4 + r;
                float dx = __fsub_rn(cxs[n0 + nl], cxm);
                float dy = __fsub_rn(cys[n0 + nl], cym);
                float d2 = __fadd_rn(__fmul_rn(dx, dx), __fmul_rn(dy, dy));
                S[nl][m] = (d2 > __uint_as_float(0x43800001u))
                               ? -__builtin_inff() : acc[r] * 0.125f;
            }
        }
    }
    __syncthreads();
    {
        int row = tid >> 3, j = tid & 7;
        float* Sp = &S[row][j * 64];
        float mx = -__builtin_inff();
        #pragma unroll
        for (int k = 0; k < 16; ++k) {
            float4 v = *reinterpret_cast<float4*>(Sp + k * 4);
            mx = fmaxf(mx, fmaxf(fmaxf(v.x, v.y), fmaxf(v.z, v.w)));
        }
        mx = fmaxf(mx, __shfl_xor(mx, 1));
        mx = fmaxf(mx, __shfl_xor(mx, 2));
        mx = fmaxf(mx, __shfl_xor(mx, 4));
        float sm = 0.f;
        #pragma unroll
        for (int k = 0; k < 16; ++k) {
            float4 v = *reinterpret_cast<float4*>(Sp + k * 4);
            v.x = __expf(v.x - mx); v.y = __expf(v.y - mx);
            v.z = __expf(v.z - mx); v.w = __expf(v.w - mx);
            sm += (v.x + v.y) + (v.z + v.w);
            *reinterpret_cast<float4*>(Sp + k * 4) = v;
        }
        sm += __shfl_xor(sm, 1);
        sm += __shfl_xor(sm, 2);
        sm += __shfl_xor(sm, 4);
        float inv = 1.0f / sm;
        float* rp = rgG + ((size_t)(bt * NN) + n0 + row) * NN + j * 64;
        #pragma unroll
        for (int k = 0; k < 16; ++k) {
            float4 a = *reinterpret_cast<float4*>(Sp + k * 4);
            a.x *= inv; a.y *= inv; a.z *= inv; a.w *= inv;
            *reinterpret_cast<float4*>(rp + k * 4) = a;
        }
    }
}

__global__ __launch_bounds__(256) void k_pool(const float* __restrict__ rgG,
                                              const float* __restrict__ X,
                                              const float* __restrict__ W,
                                              float* __restrict__ outG) {
    __shared__ short Xt[128][72];
    __shared__ short poolS[64][136];
    __shared__ short WtS[128][136];
    const int bt = blockIdx.y, n0 = blockIdx.x * 64, tid = threadIdx.x;
    const int wid = tid >> 6, lane = tid & 63;
    const int l16 = lane & 15, lg = lane >> 4;
    #pragma unroll
    for (int k = 0; k < 64; ++k) {
        int idx = k * 256 + tid;
        int f = idx >> 7, g = idx & 127;
        WtS[g][f] = f2bf(W[idx]);
    }
    f32x4 acc[8];
    #pragma unroll
    for (int ft = 0; ft < 8; ++ft) acc[ft] = f32x4{0.f, 0.f, 0.f, 0.f};
    #pragma unroll 1
    for (int mt = 0; mt < 8; ++mt) {
        __syncthreads();
        {
            int m = tid >> 2, seg = tid & 3;
            const float* src = X + ((size_t)(bt * NN + mt * 64 + m)) * NFG + seg * 32;
            #pragma unroll
            for (int k = 0; k < 8; ++k) {
                float4 v = reinterpret_cast<const float4*>(src)[k];
                int f = seg * 32 + k * 4;
                Xt[f + 0][m] = f2bf(v.x); Xt[f + 1][m] = f2bf(v.y);
                Xt[f + 2][m] = f2bf(v.z); Xt[f + 3][m] = f2bf(v.w);
            }
        }
        bfrag pa[2];
        const float* prow = rgG + ((size_t)(bt * NN + n0 + wid * 16 + l16)) * NN + mt * 64;
        #pragma unroll
        for (int kk = 0; kk < 2; ++kk) {
            float4 a = *reinterpret_cast<const float4*>(prow + kk * 32 + lg * 8);
            float4 b = *reinterpret_cast<const float4*>(prow + kk * 32 + lg * 8 + 4);
            short t[8] = { f2bf(a.x), f2bf(a.y), f2bf(a.z), f2bf(a.w),
                           f2bf(b.x), f2bf(b.y), f2bf(b.z), f2bf(b.w) };
            pa[kk] = *reinterpret_cast<bfrag*>(t);
        }
        __syncthreads();
        #pragma unroll
        for (int ft = 0; ft < 8; ++ft) {
            #pragma unroll
            for (int kk = 0; kk < 2; ++kk) {
                bfrag b = *reinterpret_cast<const bfrag*>(
                    &Xt[ft * 16 + l16][kk * 32 + lg * 8]);
                acc[ft] = __builtin_amdgcn_mfma_f32_16x16x32_bf16(pa[kk], b, acc[ft], 0, 0, 0);
            }
        }
    }
    __syncthreads();
    #pragma unroll
    for (int ft = 0; ft < 8; ++ft)
        #pragma unroll
        for (int r = 0; r < 4; ++r)
            poolS[wid * 16 + lg * 4 + r][ft * 16 + l16] = f2bf(acc[ft][r]);
    __syncthreads();
    bfrag a2[4];
    #pragma unroll
    for (int kk = 0; kk < 4; ++kk)
        a2[kk] = *reinterpret_cast<const bfrag*>(&poolS[wid * 16 + l16][kk * 32 + lg * 8]);
    #pragma unroll
    for (int gt = 0; gt < 8; ++gt) {
        f32x4 o = {0.f, 0.f, 0.f, 0.f};
        #pragma unroll
        for (int kk = 0; kk < 4; ++kk) {
            bfrag b2 = *reinterpret_cast<const bfrag*>(&WtS[gt * 16 + l16][kk * 32 + lg * 8]);
            o = __builtin_amdgcn_mfma_f32_16x16x32_bf16(a2[kk], b2, o, 0, 0, 0);
        }
        #pragma unroll
        for (int r = 0; r < 4; ++r) {
            int n = n0 + wid * 16 + lg * 4 + r;
            outG[((size_t)(bt * NN + n)) * NFG + gt * 16 + l16] = o[r];
        }
    }
}

// ---------------------------------------------------------------------------
extern "C" void kernel_launch(void* const* d_in, const int* in_sizes, int n_in,
                              void* d_out, int out_size, void* d_ws, size_t ws_size,
                              hipStream_t stream) {
    const float* X     = (const float*)d_in[0];
    const float* boxes = (const float*)d_in[1];
    const float* W     = (const float*)d_in[2];
    const float* thw   = (const float*)d_in[3];
    const float* thb   = (const float*)d_in[4];
    const float* phw   = (const float*)d_in[5];
    const float* phb   = (const float*)d_in[6];

    float* outR = (float*)d_out;                       // [256*512][128] f32
    float* rgR  = outR + (size_t)BT * NN * NFG;        // [256*512][512] f32

    const size_t TH = (size_t)BT * NN * NFR * 2;       // 16,777,216 B
    const size_t YT = (size_t)BT * NFG * NN * 2;       // 33,554,432 B
    const size_t WS_NEED = TH * 2 + YT + (size_t)NFG * NFG * 2;   // 67,141,632 B
    if (ws_size >= WS_NEED) {
        char* ws = (char*)d_ws;
        short* thetaS = (short*)(ws);
        short* phiS   = (short*)(ws + TH);
        short* YtG    = (short*)(ws + 2 * TH);
        short* WtB    = (short*)(ws + 2 * TH + YT);
        k_prep  <<<64, 256, 0, stream>>>(W, WtB);
        k_projF <<<dim3(8, BT), 256, 0, stream>>>(X, thw, thb, phw, phb, WtB,
                                                  thetaS, phiS, YtG);
        k_fused2<<<8192, 128, 0, stream>>>(thetaS, phiS, YtG, boxes, outR, rgR);
    } else {
        short* thetaS = (short*)d_out;
        short* phiS   = thetaS + (size_t)BT * NN * NFR;
        k_proj<<<dim3(8, BT), 256, 0, stream>>>(X, thw, thb, phw, phb, thetaS, phiS);
        k_sim <<<dim3(8, BT), 512, 0, stream>>>(thetaS, phiS, boxes, rgR);
        k_pool<<<dim3(8, BT), 256, 0, stream>>>(rgR, X, W, outR);
    }
}